// Round 2
// baseline (289.326 us; speedup 1.0000x reference)
//
#include <hip/hip_runtime.h>
#include <stdint.h>

#define IN_F   4096
#define OUT_F  4096
#define BATCH  4096

// legacy kernel tile params
#define BM 128
#define BN 128
#define BK 32

typedef __bf16 bf16x8 __attribute__((ext_vector_type(8)));
typedef float  f32x4  __attribute__((ext_vector_type(4)));

#define MFMA(a, b, c) __builtin_amdgcn_mfma_f32_16x16x32_bf16(a, b, c, 0, 0, 0)

// ---------- fp32 -> bf16 (round-to-nearest-even) ----------
__device__ inline unsigned short f32_to_bf16_rne(float f) {
    unsigned int u = __float_as_uint(f);
    u += 0x7FFFu + ((u >> 16) & 1u);
    return (unsigned short)(u >> 16);
}

__device__ inline unsigned int pack_bf16x2(float lo, float hi) {
    return (unsigned int)f32_to_bf16_rne(lo) | ((unsigned int)f32_to_bf16_rne(hi) << 16);
}

// One launch converts BOTH x and W. 8 floats/thread: 32B read, 16B write per lane.
__global__ void cvt2_f32_bf16(const float4* __restrict__ ia, uint4* __restrict__ oa,
                              const float4* __restrict__ ib, uint4* __restrict__ ob) {
    const int half = gridDim.x >> 1;
    const int sec  = blockIdx.x >= half;
    const float4* __restrict__ in  = sec ? ib : ia;
    uint4* __restrict__ out        = sec ? ob : oa;
    const int i = (sec ? blockIdx.x - half : blockIdx.x) * blockDim.x + threadIdx.x;
    const float4 u = in[2 * i];
    const float4 v = in[2 * i + 1];
    uint4 o;
    o.x = pack_bf16x2(u.x, u.y);
    o.y = pack_bf16x2(u.z, u.w);
    o.z = pack_bf16x2(v.x, v.y);
    o.w = pack_bf16x2(v.z, v.w);
    out[i] = o;
}

// ---------- async global->LDS, 16B per lane ----------
__device__ inline void async_load16(const void* g, void* l) {
    __builtin_amdgcn_global_load_lds(
        (const __attribute__((address_space(1))) unsigned int*)g,
        (__attribute__((address_space(3))) unsigned int*)l,
        16, 0, 0);
}

// =====================================================================
// 256x256 8-phase bf16 GEMM (m201-style): C = A * Bt^T + bias
// A: [BATCH][IN_F] bf16 bits, Bt: [OUT_F][IN_F] bf16 bits (K-contiguous)
//
// Geometry: BM=BN=256, BK=64, 512 threads = 8 waves (2M x 4N),
// per-wave output 128x64 (8 m-frags x 4 n-frags of 16x16).
// LDS 128 KiB: [buf:2][hid:4][16 KiB]; hid 0=A-ks0 1=A-ks1 2=B-ks0 3=B-ks1.
// Each half-tile: [256 rows][32 elems] (64 B rows).
// Swizzle (involution, 16B-chunk preserving): l = p ^ ((p>>4)&48)
//   => physical bits 4,5 XORed with row bits 2,3. Applied as:
//   linear global_load_lds dest + pre-swizzled global SOURCE + swizzled ds_read.
//
// Phase split (round-2 rebalance): quadrant = (ks, i-half), so ds_reads are
// {8,4,8,4} per phase (vs {10,2,12,2} in round 1) against 16 MFMA/phase:
//   p1: read A[0-3]@ks0 + B[0-3]@ks0 (8); stage A-ks1(t+1)->buf^1; MFMA i0-3@ks0
//   p2: read A[4-7]@ks0 (4);             stage B-ks0(t+2)->buf;   MFMA i4-7@ks0
//   p3: read A[0-3]@ks1 + B[0-3]@ks1 (8); stage A-ks0(t+2)->buf;  MFMA i0-3@ks1
//   p4: read A[4-7]@ks1 (4);             stage B-ks1(t+2)->buf;   MFMA i4-7@ks1
//       + s_waitcnt vmcnt(6)  (3 half-tiles in flight, never drain to 0)
// Slot safety (stage >= 1 barrier after content's last read):
//   A-ks1 slot in buf^1: content(t-1) last read p4 of t-1  -> stage at p1 ok
//   B-ks0 slot in buf:   content(t)   last read p1         -> stage at p2 ok
//   A-ks0 slot in buf:   content(t)   last read p2         -> stage at p3 ok
//   B-ks1 slot in buf:   content(t)   last read p3         -> stage at p4 ok
// vmcnt(6)@p4: outstanding = {Bks0(t+1),Aks0(t+1),Bks1(t+1),Aks1(t+1),
//   Bks0(t+2),Aks0(t+2),Bks1(t+2)} = 14 loads -> wait to 6 completes exactly
//   tile t+1's 8 loads. Tail clamp re-stages tile-63 data over itself (benign).
// =====================================================================
__global__ __launch_bounds__(512, 2)
void gemm_8ph(const unsigned short* __restrict__ A,
              const unsigned short* __restrict__ Bt,
              const float* __restrict__ bias,
              float* __restrict__ out) {
    extern __shared__ char smem[];

    const int tid  = threadIdx.x;
    const int lane = tid & 63;
    const int wv   = tid >> 6;       // 0..7
    const int wm   = wv >> 2;        // 0..1  (M half: 128 rows)
    const int wn   = wv & 3;         // 0..3  (N quarter: 64 cols)

    // XCD-aware bijective swizzle (256 wgs, 256 % 8 == 0)
    const int bid = blockIdx.x;
    const int swz = (bid & 7) * 32 + (bid >> 3);
    const int m0  = (swz >> 4) * 256;
    const int n0  = (swz & 15) * 256;

    // ---- staging geometry: linear LDS dest, pre-swizzled global src ----
    const int p0   = tid * 16;
    const int l0   = p0 ^ ((p0 >> 4) & 48);
    const int srow = l0 >> 6;          // 0..127  (q=1 adds 128)
    const int scol = (l0 & 63) >> 1;   // elem 0..31 (multiple of 8)
    const unsigned short* sA = A  + (size_t)(m0 + srow) * IN_F + scol;
    const unsigned short* sB = Bt + (size_t)(n0 + srow) * IN_F + scol;
    char* const ldsw = smem + wv * 1024;   // wave-uniform staging base

    auto stage = [&](const unsigned short* g, int hid, int buf) {
        char* d = ldsw + buf * 65536 + hid * 16384;
        async_load16(g, d);                                  // rows 0..127
        async_load16(g + (size_t)128 * IN_F, d + 8192);      // rows 128..255
    };

    // ---- prologue: tile 0 (4 halves), then 3 halves of tile 1 ----
    stage(sA,      0, 0);   // A-ks0(0)
    stage(sB,      2, 0);   // B-ks0(0)
    stage(sA + 32, 1, 0);   // A-ks1(0)
    stage(sB + 32, 3, 0);   // B-ks1(0)

    // frag-read offsets (VALU work overlaps the in-flight loads)
    // MFMA A/B operand: row = lane&15, k = (lane>>4)*8 + j
    const int fr  = lane & 15;
    const int kq2 = ((lane >> 4) << 3) * 2;      // byte offset in 64B row: 0,16,32,48
    const int sx  = (fr & 12) << 2;              // row bits 2,3 == fr bits 2,3
    int aro[8], bro[4];
    #pragma unroll
    for (int i = 0; i < 8; ++i)
        aro[i] = (wm * 128 + i * 16 + fr) * 64 + (kq2 ^ sx);
    #pragma unroll
    for (int j = 0; j < 4; ++j)
        bro[j] = (wn * 64 + j * 16 + fr) * 64 + (kq2 ^ sx);

    f32x4 acc[8][4] = {};

    // match steady-state issue order of iter t-1: p2 Bks0, p3 Aks0, p4 Bks1
    stage(sB + 64, 2, 1);   // B-ks0(1)
    stage(sA + 64, 0, 1);   // A-ks0(1)
    stage(sB + 96, 3, 1);   // B-ks1(1)
    asm volatile("s_waitcnt vmcnt(6)" ::: "memory");   // tile 0 fully staged; 3 in flight
    __builtin_amdgcn_s_barrier();

    for (int t = 0; t < 64; ++t) {
        const int buf = t & 1;
        const char* base = smem + buf * 65536;
        const int kt1 = (t + 1 < 64 ? t + 1 : 63) * 64;  // clamp keeps vmcnt arithmetic uniform
        const int kt2 = (t + 2 < 64 ? t + 2 : 63) * 64;

        bf16x8 a0, a1, a2, a3, b0, b1, b2, b3;

        // ---------------- phase 1: ks=0, i={0..3} (8 reads) ----------------
        a0 = *(const bf16x8*)(base + aro[0]);
        a1 = *(const bf16x8*)(base + aro[1]);
        a2 = *(const bf16x8*)(base + aro[2]);
        a3 = *(const bf16x8*)(base + aro[3]);
        b0 = *(const bf16x8*)(base + 2 * 16384 + bro[0]);
        b1 = *(const bf16x8*)(base + 2 * 16384 + bro[1]);
        b2 = *(const bf16x8*)(base + 2 * 16384 + bro[2]);
        b3 = *(const bf16x8*)(base + 2 * 16384 + bro[3]);
        stage(sA + kt1 + 32, 1, buf ^ 1);            // A-ks1(t+1)
        __builtin_amdgcn_s_barrier();
        asm volatile("s_waitcnt lgkmcnt(0)" ::: "memory");
        __builtin_amdgcn_s_setprio(1);
        acc[0][0] = MFMA(a0, b0, acc[0][0]); acc[0][1] = MFMA(a0, b1, acc[0][1]);
        acc[0][2] = MFMA(a0, b2, acc[0][2]); acc[0][3] = MFMA(a0, b3, acc[0][3]);
        acc[1][0] = MFMA(a1, b0, acc[1][0]); acc[1][1] = MFMA(a1, b1, acc[1][1]);
        acc[1][2] = MFMA(a1, b2, acc[1][2]); acc[1][3] = MFMA(a1, b3, acc[1][3]);
        acc[2][0] = MFMA(a2, b0, acc[2][0]); acc[2][1] = MFMA(a2, b1, acc[2][1]);
        acc[2][2] = MFMA(a2, b2, acc[2][2]); acc[2][3] = MFMA(a2, b3, acc[2][3]);
        acc[3][0] = MFMA(a3, b0, acc[3][0]); acc[3][1] = MFMA(a3, b1, acc[3][1]);
        acc[3][2] = MFMA(a3, b2, acc[3][2]); acc[3][3] = MFMA(a3, b3, acc[3][3]);
        __builtin_amdgcn_s_setprio(0);
        __builtin_amdgcn_s_barrier();

        // ---------------- phase 2: ks=0, i={4..7} (4 reads; B held in regs) ----------------
        a0 = *(const bf16x8*)(base + aro[4]);
        a1 = *(const bf16x8*)(base + aro[5]);
        a2 = *(const bf16x8*)(base + aro[6]);
        a3 = *(const bf16x8*)(base + aro[7]);
        stage(sB + kt2, 2, buf);                     // B-ks0(t+2)
        __builtin_amdgcn_s_barrier();
        asm volatile("s_waitcnt lgkmcnt(0)" ::: "memory");
        __builtin_amdgcn_s_setprio(1);
        acc[4][0] = MFMA(a0, b0, acc[4][0]); acc[4][1] = MFMA(a0, b1, acc[4][1]);
        acc[4][2] = MFMA(a0, b2, acc[4][2]); acc[4][3] = MFMA(a0, b3, acc[4][3]);
        acc[5][0] = MFMA(a1, b0, acc[5][0]); acc[5][1] = MFMA(a1, b1, acc[5][1]);
        acc[5][2] = MFMA(a1, b2, acc[5][2]); acc[5][3] = MFMA(a1, b3, acc[5][3]);
        acc[6][0] = MFMA(a2, b0, acc[6][0]); acc[6][1] = MFMA(a2, b1, acc[6][1]);
        acc[6][2] = MFMA(a2, b2, acc[6][2]); acc[6][3] = MFMA(a2, b3, acc[6][3]);
        acc[7][0] = MFMA(a3, b0, acc[7][0]); acc[7][1] = MFMA(a3, b1, acc[7][1]);
        acc[7][2] = MFMA(a3, b2, acc[7][2]); acc[7][3] = MFMA(a3, b3, acc[7][3]);
        __builtin_amdgcn_s_setprio(0);
        __builtin_amdgcn_s_barrier();

        // ---------------- phase 3: ks=1, i={0..3} (8 reads) ----------------
        a0 = *(const bf16x8*)(base + 16384 + aro[0]);
        a1 = *(const bf16x8*)(base + 16384 + aro[1]);
        a2 = *(const bf16x8*)(base + 16384 + aro[2]);
        a3 = *(const bf16x8*)(base + 16384 + aro[3]);
        b0 = *(const bf16x8*)(base + 3 * 16384 + bro[0]);
        b1 = *(const bf16x8*)(base + 3 * 16384 + bro[1]);
        b2 = *(const bf16x8*)(base + 3 * 16384 + bro[2]);
        b3 = *(const bf16x8*)(base + 3 * 16384 + bro[3]);
        stage(sA + kt2, 0, buf);                     // A-ks0(t+2)
        __builtin_amdgcn_s_barrier();
        asm volatile("s_waitcnt lgkmcnt(0)" ::: "memory");
        __builtin_amdgcn_s_setprio(1);
        acc[0][0] = MFMA(a0, b0, acc[0][0]); acc[0][1] = MFMA(a0, b1, acc[0][1]);
        acc[0][2] = MFMA(a0, b2, acc[0][2]); acc[0][3] = MFMA(a0, b3, acc[0][3]);
        acc[1][0] = MFMA(a1, b0, acc[1][0]); acc[1][1] = MFMA(a1, b1, acc[1][1]);
        acc[1][2] = MFMA(a1, b2, acc[1][2]); acc[1][3] = MFMA(a1, b3, acc[1][3]);
        acc[2][0] = MFMA(a2, b0, acc[2][0]); acc[2][1] = MFMA(a2, b1, acc[2][1]);
        acc[2][2] = MFMA(a2, b2, acc[2][2]); acc[2][3] = MFMA(a2, b3, acc[2][3]);
        acc[3][0] = MFMA(a3, b0, acc[3][0]); acc[3][1] = MFMA(a3, b1, acc[3][1]);
        acc[3][2] = MFMA(a3, b2, acc[3][2]); acc[3][3] = MFMA(a3, b3, acc[3][3]);
        __builtin_amdgcn_s_setprio(0);
        __builtin_amdgcn_s_barrier();

        // ---------------- phase 4: ks=1, i={4..7} (4 reads) ----------------
        a0 = *(const bf16x8*)(base + 16384 + aro[4]);
        a1 = *(const bf16x8*)(base + 16384 + aro[5]);
        a2 = *(const bf16x8*)(base + 16384 + aro[6]);
        a3 = *(const bf16x8*)(base + 16384 + aro[7]);
        stage(sB + kt2 + 32, 3, buf);                // B-ks1(t+2)
        __builtin_amdgcn_s_barrier();
        asm volatile("s_waitcnt lgkmcnt(0)" ::: "memory");
        __builtin_amdgcn_s_setprio(1);
        acc[4][0] = MFMA(a0, b0, acc[4][0]); acc[4][1] = MFMA(a0, b1, acc[4][1]);
        acc[4][2] = MFMA(a0, b2, acc[4][2]); acc[4][3] = MFMA(a0, b3, acc[4][3]);
        acc[5][0] = MFMA(a1, b0, acc[5][0]); acc[5][1] = MFMA(a1, b1, acc[5][1]);
        acc[5][2] = MFMA(a1, b2, acc[5][2]); acc[5][3] = MFMA(a1, b3, acc[5][3]);
        acc[6][0] = MFMA(a2, b0, acc[6][0]); acc[6][1] = MFMA(a2, b1, acc[6][1]);
        acc[6][2] = MFMA(a2, b2, acc[6][2]); acc[6][3] = MFMA(a2, b3, acc[6][3]);
        acc[7][0] = MFMA(a3, b0, acc[7][0]); acc[7][1] = MFMA(a3, b1, acc[7][1]);
        acc[7][2] = MFMA(a3, b2, acc[7][2]); acc[7][3] = MFMA(a3, b3, acc[7][3]);
        __builtin_amdgcn_s_setprio(0);
        asm volatile("s_waitcnt vmcnt(6)" ::: "memory");  // tile t+1 complete; 3 halves in flight
        __builtin_amdgcn_s_barrier();
    }

    asm volatile("s_waitcnt vmcnt(0)" ::: "memory");  // drain tail garbage stages before exit

    // ---- epilogue. C/D layout (verified m89/m91): col=lane&15, row=(lane>>4)*4+reg ----
    const int ocol = n0 + wn * 64;
    int oc = ocol + fr;
    asm volatile("" : "+v"(oc));   // launder: keep bias loads out of the counted-vmcnt loop
    float bj[4];
    #pragma unroll
    for (int j = 0; j < 4; ++j) bj[j] = bias[oc + j * 16];
    const int rsel = (lane >> 4) * 4;
    #pragma unroll
    for (int i = 0; i < 8; ++i) {
        #pragma unroll
        for (int v = 0; v < 4; ++v) {
            const int row = m0 + wm * 128 + i * 16 + rsel + v;
            float* orow = out + (size_t)row * OUT_F + ocol + fr;
            #pragma unroll
            for (int j = 0; j < 4; ++j)
                orow[j * 16] = acc[i][j][v] + bj[j];
        }
    }
}

// =====================================================================
// Legacy verified m97-structure kernel — fallback if 128 KiB dyn-LDS
// attribute can't be set.
// =====================================================================
__global__ void gemm_bt_bf16(const unsigned short* __restrict__ A,
                             const unsigned short* __restrict__ Bt,
                             const float* __restrict__ bias,
                             float* __restrict__ out) {
    __shared__ unsigned short lsA[BM * BK];
    __shared__ unsigned short lsB[BN * BK];

    const int tid  = threadIdx.x;
    const int lane = tid & 63;
    const int wv   = tid >> 6;
    const int wmm  = (wv & 1) * 64;
    const int wnn  = (wv >> 1) * 64;

    const int m0 = blockIdx.y * BM;
    const int n0 = blockIdx.x * BN;

    const int srow = lane >> 2;
    const int scol = (lane & 3) * 8;

    const unsigned short* gA0 = A  + (size_t)(m0 + wv * 32 + srow) * IN_F + scol;
    const unsigned short* gA1 = gA0 + 16 * (size_t)IN_F;
    const unsigned short* gB0 = Bt + (size_t)(n0 + wv * 32 + srow) * IN_F + scol;
    const unsigned short* gB1 = gB0 + 16 * (size_t)IN_F;

    unsigned short* lA0 = &lsA[(wv * 32)      * BK];
    unsigned short* lA1 = &lsA[(wv * 32 + 16) * BK];
    unsigned short* lB0 = &lsB[(wv * 32)      * BK];
    unsigned short* lB1 = &lsB[(wv * 32 + 16) * BK];

    const int fr = lane & 15;
    const int kq = (lane >> 4) * 8;

    f32x4 acc[4][4] = {};

    for (int kt = 0; kt < IN_F; kt += BK) {
        async_load16(gA0, lA0);
        async_load16(gA1, lA1);
        async_load16(gB0, lB0);
        async_load16(gB1, lB1);
        gA0 += BK; gA1 += BK; gB0 += BK; gB1 += BK;
        __syncthreads();

        bf16x8 aF[4], bF[4];
        #pragma unroll
        for (int i = 0; i < 4; ++i)
            aF[i] = *(const bf16x8*)&lsA[(wmm + i * 16 + fr) * BK + kq];
        #pragma unroll
        for (int j = 0; j < 4; ++j)
            bF[j] = *(const bf16x8*)&lsB[(wnn + j * 16 + fr) * BK + kq];

        #pragma unroll
        for (int i = 0; i < 4; ++i)
            #pragma unroll
            for (int j = 0; j < 4; ++j)
                acc[i][j] = MFMA(aF[i], bF[j], acc[i][j]);
        __syncthreads();
    }

    const int ocol = n0 + wnn;
    float bj[4];
    #pragma unroll
    for (int j = 0; j < 4; ++j) bj[j] = bias[ocol + j * 16 + fr];

    const int rsel = (lane >> 4) * 4;
    #pragma unroll
    for (int i = 0; i < 4; ++i) {
        #pragma unroll
        for (int v = 0; v < 4; ++v) {
            const int row = m0 + wmm + i * 16 + rsel + v;
            float* orow = out + (size_t)row * OUT_F + ocol + fr;
            #pragma unroll
            for (int j = 0; j < 4; ++j)
                orow[j * 16] = acc[i][j][v] + bj[j];
        }
    }
}

// ---------- fallback: correct fp32 tiled GEMM (only if ws too small) ----------
__global__ void fb_gemm(const float* __restrict__ A, const float* __restrict__ W,
                        const float* __restrict__ bias, float* __restrict__ out) {
    __shared__ float tA[16][17];
    __shared__ float tW[16][17];
    const int tx = threadIdx.x, ty = threadIdx.y;
    const int row = blockIdx.y * 16 + ty;
    const int col = blockIdx.x * 16 + tx;
    float s = 0.f;
    for (int k = 0; k < IN_F; k += 16) {
        tA[ty][tx] = A[(size_t)row * IN_F + k + tx];
        tW[ty][tx] = W[(size_t)(blockIdx.x * 16 + ty) * IN_F + k + tx];
        __syncthreads();
        #pragma unroll
        for (int kk = 0; kk < 16; ++kk) s += tA[ty][kk] * tW[tx][kk];
        __syncthreads();
    }
    out[(size_t)row * OUT_F + col] = s + bias[col];
}

extern "C" void kernel_launch(void* const* d_in, const int* in_sizes, int n_in,
                              void* d_out, int out_size, void* d_ws, size_t ws_size,
                              hipStream_t stream) {
    const float* x = (const float*)d_in[0];
    const float* W = (const float*)d_in[1];
    const float* b = (const float*)d_in[2];
    float* out = (float*)d_out;

    const size_t elems      = (size_t)BATCH * IN_F;  // 16.7M per matrix
    const size_t bf16_bytes = elems * 2;             // 32 MiB each

    if (ws_size >= 2 * bf16_bytes) {
        unsigned short* xb = (unsigned short*)d_ws;
        unsigned short* wb = (unsigned short*)((char*)d_ws + bf16_bytes);

        const int blocks_per = (int)(elems / 8 / 256);   // 8192 per matrix
        cvt2_f32_bf16<<<blocks_per * 2, 256, 0, stream>>>(
            (const float4*)x, (uint4*)xb, (const float4*)W, (uint4*)wb);

        static int use8 = -1;
        if (use8 < 0) {
            use8 = (hipFuncSetAttribute((const void*)gemm_8ph,
                        hipFuncAttributeMaxDynamicSharedMemorySize,
                        131072) == hipSuccess) ? 1 : 0;
        }
        if (use8) {
            gemm_8ph<<<256, 512, 131072, stream>>>(xb, wb, b, out);
        } else {
            dim3 grid(OUT_F / BN, BATCH / BM);
            gemm_bt_bf16<<<grid, 256, 0, stream>>>(xb, wb, b, out);
        }
    } else {
        dim3 grid(OUT_F / 16, BATCH / 16);
        fb_gemm<<<grid, dim3(16, 16), 0, stream>>>(x, W, b, out);
    }
}

// Round 3
// 279.995 us; speedup vs baseline: 1.0333x; 1.0333x over previous
//
#include <hip/hip_runtime.h>
#include <stdint.h>

#define IN_F   4096
#define OUT_F  4096
#define BATCH  4096

// legacy kernel tile params
#define BM 128
#define BN 128
#define BK 32

typedef __bf16 bf16x8 __attribute__((ext_vector_type(8)));
typedef float  f32x4  __attribute__((ext_vector_type(4)));

#define MFMA(a, b, c) __builtin_amdgcn_mfma_f32_16x16x32_bf16(a, b, c, 0, 0, 0)

// ---------- fp32 -> bf16 (round-to-nearest-even) ----------
__device__ inline unsigned short f32_to_bf16_rne(float f) {
    unsigned int u = __float_as_uint(f);
    u += 0x7FFFu + ((u >> 16) & 1u);
    return (unsigned short)(u >> 16);
}

__device__ inline unsigned int pack_bf16x2(float lo, float hi) {
    return (unsigned int)f32_to_bf16_rne(lo) | ((unsigned int)f32_to_bf16_rne(hi) << 16);
}

// One launch converts BOTH x and W. 8 floats/thread: 32B read, 16B write per lane.
__global__ void cvt2_f32_bf16(const float4* __restrict__ ia, uint4* __restrict__ oa,
                              const float4* __restrict__ ib, uint4* __restrict__ ob) {
    const int half = gridDim.x >> 1;
    const int sec  = blockIdx.x >= half;
    const float4* __restrict__ in  = sec ? ib : ia;
    uint4* __restrict__ out        = sec ? ob : oa;
    const int i = (sec ? blockIdx.x - half : blockIdx.x) * blockDim.x + threadIdx.x;
    const float4 u = in[2 * i];
    const float4 v = in[2 * i + 1];
    uint4 o;
    o.x = pack_bf16x2(u.x, u.y);
    o.y = pack_bf16x2(u.z, u.w);
    o.z = pack_bf16x2(v.x, v.y);
    o.w = pack_bf16x2(v.z, v.w);
    out[i] = o;
}

// ---------- async global->LDS, 16B per lane ----------
__device__ inline void async_load16(const void* g, void* l) {
    __builtin_amdgcn_global_load_lds(
        (const __attribute__((address_space(1))) unsigned int*)g,
        (__attribute__((address_space(3))) unsigned int*)l,
        16, 0, 0);
}

// =====================================================================
// 256x256 8-phase bf16 GEMM (m201-style): C = A * Bt^T + bias
// A: [BATCH][IN_F] bf16 bits, Bt: [OUT_F][IN_F] bf16 bits (K-contiguous)
//
// Geometry: BM=BN=256, BK=64, 512 threads = 8 waves (2M x 4N),
// per-wave output 128x64 (8 m-frags x 4 n-frags of 16x16).
// LDS 128 KiB: [buf:2][hid:4][16 KiB]; hid 0=A-ks0 1=A-ks1 2=B-ks0 3=B-ks1.
// Each half-tile: [256 rows][32 elems] (64 B rows).
//
// Swizzle (round-3 fix: 3-bit, conflict-free): l = p ^ (((p>>7)&7)<<4)
//   XORs physical bits 4,5,6 with row bits 1,2,3. Involution (mask bits 7-9
//   untouched), 16B-chunk preserving (mask >= bit 4). ds_read slot bits
//   become {kq0^fr1, kq1^fr2, fr0^fr3}: any 8 consecutive lanes sweep all
//   8 16B-slots -> all 32 banks exactly once -> conflict-free b128 reads.
//   (Round-1/2 swizzle only XORed bits 4-5 with row bits 2-3: slot depended
//   on fr0,fr2 only -> 2-way conflict -> measured 1.26e7 SQ_LDS_BANK_CONFLICT.)
// Applied as: linear global_load_lds dest + pre-swizzled global SOURCE +
// swizzled ds_read (both-sides-or-neither, rule #21).
//
// Phase split: quadrant = (ks, i-half), ds_reads {8,4,8,4} per phase:
//   p1: read A[0-3]@ks0 + B[0-3]@ks0 (8); stage A-ks1(t+1)->buf^1; MFMA i0-3@ks0
//   p2: read A[4-7]@ks0 (4);             stage B-ks0(t+2)->buf;   MFMA i4-7@ks0
//   p3: read A[0-3]@ks1 + B[0-3]@ks1 (8); stage A-ks0(t+2)->buf;  MFMA i0-3@ks1
//   p4: read A[4-7]@ks1 (4);             stage B-ks1(t+2)->buf;   MFMA i4-7@ks1
//       + s_waitcnt vmcnt(6)  (3 half-tiles in flight, never drain to 0)
// Slot safety (stage >= 1 barrier after content's last read):
//   A-ks1 slot in buf^1: content(t-1) last read p4 of t-1  -> stage at p1 ok
//   B-ks0 slot in buf:   content(t)   last read p1         -> stage at p2 ok
//   A-ks0 slot in buf:   content(t)   last read p2         -> stage at p3 ok
//   B-ks1 slot in buf:   content(t)   last read p3         -> stage at p4 ok
// vmcnt(6)@p4: outstanding = {Bks0(t+1),Aks0(t+1),Bks1(t+1),Aks1(t+1),
//   Bks0(t+2),Aks0(t+2),Bks1(t+2)} = 14 loads -> wait to 6 completes exactly
//   tile t+1's 8 loads. Tail clamp re-stages tile-63 data over itself (benign).
// =====================================================================
__global__ __launch_bounds__(512, 2)
void gemm_8ph(const unsigned short* __restrict__ A,
              const unsigned short* __restrict__ Bt,
              const float* __restrict__ bias,
              float* __restrict__ out) {
    extern __shared__ char smem[];

    const int tid  = threadIdx.x;
    const int lane = tid & 63;
    const int wv   = tid >> 6;       // 0..7
    const int wm   = wv >> 2;        // 0..1  (M half: 128 rows)
    const int wn   = wv & 3;         // 0..3  (N quarter: 64 cols)

    // XCD-aware bijective swizzle (256 wgs, 256 % 8 == 0)
    const int bid = blockIdx.x;
    const int swz = (bid & 7) * 32 + (bid >> 3);
    const int m0  = (swz >> 4) * 256;
    const int n0  = (swz & 15) * 256;

    // ---- staging geometry: linear LDS dest, pre-swizzled global src ----
    // thread t writes phys p0 = tid*16 (+q*8192); it must carry logical
    // l0 = p0 ^ (((p0>>7)&7)<<4)  (involution of the read-side swizzle).
    const int p0   = tid * 16;
    const int l0   = p0 ^ (((p0 >> 7) & 7) << 4);
    const int srow = l0 >> 6;          // 0..127  (q=1 adds 128)
    const int scol = (l0 & 63) >> 1;   // elem 0..31 (multiple of 8)
    const unsigned short* sA = A  + (size_t)(m0 + srow) * IN_F + scol;
    const unsigned short* sB = Bt + (size_t)(n0 + srow) * IN_F + scol;
    char* const ldsw = smem + wv * 1024;   // wave-uniform staging base

    auto stage = [&](const unsigned short* g, int hid, int buf) {
        char* d = ldsw + buf * 65536 + hid * 16384;
        async_load16(g, d);                                  // rows 0..127
        async_load16(g + (size_t)128 * IN_F, d + 8192);      // rows 128..255
    };

    // ---- prologue: tile 0 (4 halves), then 3 halves of tile 1 ----
    stage(sA,      0, 0);   // A-ks0(0)
    stage(sB,      2, 0);   // B-ks0(0)
    stage(sA + 32, 1, 0);   // A-ks1(0)
    stage(sB + 32, 3, 0);   // B-ks1(0)

    // frag-read offsets (VALU work overlaps the in-flight loads)
    // MFMA A/B operand: row = lane&15, k = (lane>>4)*8 + j
    // phys = (row*64 + kq2) ^ sx, sx = row bits 1-3 -> bits 4-6.
    // row = 16*m + fr  =>  (row>>1)&7 == fr>>1  =>  sx = (fr&14)<<3.
    const int fr  = lane & 15;
    const int kq2 = ((lane >> 4) << 3) * 2;      // byte offset in 64B row: 0,16,32,48
    const int sx  = (fr & 14) << 3;              // swizzle mask, bits 4-6
    int aro[8], bro[4];
    #pragma unroll
    for (int i = 0; i < 8; ++i)
        aro[i] = ((wm * 128 + i * 16 + fr) * 64 + kq2) ^ sx;
    #pragma unroll
    for (int j = 0; j < 4; ++j)
        bro[j] = ((wn * 64 + j * 16 + fr) * 64 + kq2) ^ sx;

    f32x4 acc[8][4] = {};

    // match steady-state issue order of iter t-1: p2 Bks0, p3 Aks0, p4 Bks1
    stage(sB + 64, 2, 1);   // B-ks0(1)
    stage(sA + 64, 0, 1);   // A-ks0(1)
    stage(sB + 96, 3, 1);   // B-ks1(1)
    asm volatile("s_waitcnt vmcnt(6)" ::: "memory");   // tile 0 fully staged; 3 in flight
    __builtin_amdgcn_s_barrier();

    for (int t = 0; t < 64; ++t) {
        const int buf = t & 1;
        const char* base = smem + buf * 65536;
        const int kt1 = (t + 1 < 64 ? t + 1 : 63) * 64;  // clamp keeps vmcnt arithmetic uniform
        const int kt2 = (t + 2 < 64 ? t + 2 : 63) * 64;

        bf16x8 a0, a1, a2, a3, b0, b1, b2, b3;

        // ---------------- phase 1: ks=0, i={0..3} (8 reads) ----------------
        a0 = *(const bf16x8*)(base + aro[0]);
        a1 = *(const bf16x8*)(base + aro[1]);
        a2 = *(const bf16x8*)(base + aro[2]);
        a3 = *(const bf16x8*)(base + aro[3]);
        b0 = *(const bf16x8*)(base + 2 * 16384 + bro[0]);
        b1 = *(const bf16x8*)(base + 2 * 16384 + bro[1]);
        b2 = *(const bf16x8*)(base + 2 * 16384 + bro[2]);
        b3 = *(const bf16x8*)(base + 2 * 16384 + bro[3]);
        stage(sA + kt1 + 32, 1, buf ^ 1);            // A-ks1(t+1)
        __builtin_amdgcn_s_barrier();
        asm volatile("s_waitcnt lgkmcnt(0)" ::: "memory");
        __builtin_amdgcn_s_setprio(1);
        acc[0][0] = MFMA(a0, b0, acc[0][0]); acc[0][1] = MFMA(a0, b1, acc[0][1]);
        acc[0][2] = MFMA(a0, b2, acc[0][2]); acc[0][3] = MFMA(a0, b3, acc[0][3]);
        acc[1][0] = MFMA(a1, b0, acc[1][0]); acc[1][1] = MFMA(a1, b1, acc[1][1]);
        acc[1][2] = MFMA(a1, b2, acc[1][2]); acc[1][3] = MFMA(a1, b3, acc[1][3]);
        acc[2][0] = MFMA(a2, b0, acc[2][0]); acc[2][1] = MFMA(a2, b1, acc[2][1]);
        acc[2][2] = MFMA(a2, b2, acc[2][2]); acc[2][3] = MFMA(a2, b3, acc[2][3]);
        acc[3][0] = MFMA(a3, b0, acc[3][0]); acc[3][1] = MFMA(a3, b1, acc[3][1]);
        acc[3][2] = MFMA(a3, b2, acc[3][2]); acc[3][3] = MFMA(a3, b3, acc[3][3]);
        __builtin_amdgcn_s_setprio(0);
        __builtin_amdgcn_s_barrier();

        // ---------------- phase 2: ks=0, i={4..7} (4 reads; B held in regs) ----------------
        a0 = *(const bf16x8*)(base + aro[4]);
        a1 = *(const bf16x8*)(base + aro[5]);
        a2 = *(const bf16x8*)(base + aro[6]);
        a3 = *(const bf16x8*)(base + aro[7]);
        stage(sB + kt2, 2, buf);                     // B-ks0(t+2)
        __builtin_amdgcn_s_barrier();
        asm volatile("s_waitcnt lgkmcnt(0)" ::: "memory");
        __builtin_amdgcn_s_setprio(1);
        acc[4][0] = MFMA(a0, b0, acc[4][0]); acc[4][1] = MFMA(a0, b1, acc[4][1]);
        acc[4][2] = MFMA(a0, b2, acc[4][2]); acc[4][3] = MFMA(a0, b3, acc[4][3]);
        acc[5][0] = MFMA(a1, b0, acc[5][0]); acc[5][1] = MFMA(a1, b1, acc[5][1]);
        acc[5][2] = MFMA(a1, b2, acc[5][2]); acc[5][3] = MFMA(a1, b3, acc[5][3]);
        acc[6][0] = MFMA(a2, b0, acc[6][0]); acc[6][1] = MFMA(a2, b1, acc[6][1]);
        acc[6][2] = MFMA(a2, b2, acc[6][2]); acc[6][3] = MFMA(a2, b3, acc[6][3]);
        acc[7][0] = MFMA(a3, b0, acc[7][0]); acc[7][1] = MFMA(a3, b1, acc[7][1]);
        acc[7][2] = MFMA(a3, b2, acc[7][2]); acc[7][3] = MFMA(a3, b3, acc[7][3]);
        __builtin_amdgcn_s_setprio(0);
        __builtin_amdgcn_s_barrier();

        // ---------------- phase 3: ks=1, i={0..3} (8 reads) ----------------
        a0 = *(const bf16x8*)(base + 16384 + aro[0]);
        a1 = *(const bf16x8*)(base + 16384 + aro[1]);
        a2 = *(const bf16x8*)(base + 16384 + aro[2]);
        a3 = *(const bf16x8*)(base + 16384 + aro[3]);
        b0 = *(const bf16x8*)(base + 3 * 16384 + bro[0]);
        b1 = *(const bf16x8*)(base + 3 * 16384 + bro[1]);
        b2 = *(const bf16x8*)(base + 3 * 16384 + bro[2]);
        b3 = *(const bf16x8*)(base + 3 * 16384 + bro[3]);
        stage(sA + kt2, 0, buf);                     // A-ks0(t+2)
        __builtin_amdgcn_s_barrier();
        asm volatile("s_waitcnt lgkmcnt(0)" ::: "memory");
        __builtin_amdgcn_s_setprio(1);
        acc[0][0] = MFMA(a0, b0, acc[0][0]); acc[0][1] = MFMA(a0, b1, acc[0][1]);
        acc[0][2] = MFMA(a0, b2, acc[0][2]); acc[0][3] = MFMA(a0, b3, acc[0][3]);
        acc[1][0] = MFMA(a1, b0, acc[1][0]); acc[1][1] = MFMA(a1, b1, acc[1][1]);
        acc[1][2] = MFMA(a1, b2, acc[1][2]); acc[1][3] = MFMA(a1, b3, acc[1][3]);
        acc[2][0] = MFMA(a2, b0, acc[2][0]); acc[2][1] = MFMA(a2, b1, acc[2][1]);
        acc[2][2] = MFMA(a2, b2, acc[2][2]); acc[2][3] = MFMA(a2, b3, acc[2][3]);
        acc[3][0] = MFMA(a3, b0, acc[3][0]); acc[3][1] = MFMA(a3, b1, acc[3][1]);
        acc[3][2] = MFMA(a3, b2, acc[3][2]); acc[3][3] = MFMA(a3, b3, acc[3][3]);
        __builtin_amdgcn_s_setprio(0);
        __builtin_amdgcn_s_barrier();

        // ---------------- phase 4: ks=1, i={4..7} (4 reads) ----------------
        a0 = *(const bf16x8*)(base + 16384 + aro[4]);
        a1 = *(const bf16x8*)(base + 16384 + aro[5]);
        a2 = *(const bf16x8*)(base + 16384 + aro[6]);
        a3 = *(const bf16x8*)(base + 16384 + aro[7]);
        stage(sB + kt2 + 32, 3, buf);                // B-ks1(t+2)
        __builtin_amdgcn_s_barrier();
        asm volatile("s_waitcnt lgkmcnt(0)" ::: "memory");
        __builtin_amdgcn_s_setprio(1);
        acc[4][0] = MFMA(a0, b0, acc[4][0]); acc[4][1] = MFMA(a0, b1, acc[4][1]);
        acc[4][2] = MFMA(a0, b2, acc[4][2]); acc[4][3] = MFMA(a0, b3, acc[4][3]);
        acc[5][0] = MFMA(a1, b0, acc[5][0]); acc[5][1] = MFMA(a1, b1, acc[5][1]);
        acc[5][2] = MFMA(a1, b2, acc[5][2]); acc[5][3] = MFMA(a1, b3, acc[5][3]);
        acc[6][0] = MFMA(a2, b0, acc[6][0]); acc[6][1] = MFMA(a2, b1, acc[6][1]);
        acc[6][2] = MFMA(a2, b2, acc[6][2]); acc[6][3] = MFMA(a2, b3, acc[6][3]);
        acc[7][0] = MFMA(a3, b0, acc[7][0]); acc[7][1] = MFMA(a3, b1, acc[7][1]);
        acc[7][2] = MFMA(a3, b2, acc[7][2]); acc[7][3] = MFMA(a3, b3, acc[7][3]);
        __builtin_amdgcn_s_setprio(0);
        asm volatile("s_waitcnt vmcnt(6)" ::: "memory");  // tile t+1 complete; 3 halves in flight
        __builtin_amdgcn_s_barrier();
    }

    asm volatile("s_waitcnt vmcnt(0)" ::: "memory");  // drain tail garbage stages before exit

    // ---- epilogue. C/D layout (verified m89/m91): col=lane&15, row=(lane>>4)*4+reg ----
    const int ocol = n0 + wn * 64;
    int oc = ocol + fr;
    asm volatile("" : "+v"(oc));   // launder: keep bias loads out of the counted-vmcnt loop
    float bj[4];
    #pragma unroll
    for (int j = 0; j < 4; ++j) bj[j] = bias[oc + j * 16];
    const int rsel = (lane >> 4) * 4;
    #pragma unroll
    for (int i = 0; i < 8; ++i) {
        #pragma unroll
        for (int v = 0; v < 4; ++v) {
            const int row = m0 + wm * 128 + i * 16 + rsel + v;
            float* orow = out + (size_t)row * OUT_F + ocol + fr;
            #pragma unroll
            for (int j = 0; j < 4; ++j)
                orow[j * 16] = acc[i][j][v] + bj[j];
        }
    }
}

// =====================================================================
// Legacy verified m97-structure kernel — fallback if 128 KiB dyn-LDS
// attribute can't be set.
// =====================================================================
__global__ void gemm_bt_bf16(const unsigned short* __restrict__ A,
                             const unsigned short* __restrict__ Bt,
                             const float* __restrict__ bias,
                             float* __restrict__ out) {
    __shared__ unsigned short lsA[BM * BK];
    __shared__ unsigned short lsB[BN * BK];

    const int tid  = threadIdx.x;
    const int lane = tid & 63;
    const int wv   = tid >> 6;
    const int wmm  = (wv & 1) * 64;
    const int wnn  = (wv >> 1) * 64;

    const int m0 = blockIdx.y * BM;
    const int n0 = blockIdx.x * BN;

    const int srow = lane >> 2;
    const int scol = (lane & 3) * 8;

    const unsigned short* gA0 = A  + (size_t)(m0 + wv * 32 + srow) * IN_F + scol;
    const unsigned short* gA1 = gA0 + 16 * (size_t)IN_F;
    const unsigned short* gB0 = Bt + (size_t)(n0 + wv * 32 + srow) * IN_F + scol;
    const unsigned short* gB1 = gB0 + 16 * (size_t)IN_F;

    unsigned short* lA0 = &lsA[(wv * 32)      * BK];
    unsigned short* lA1 = &lsA[(wv * 32 + 16) * BK];
    unsigned short* lB0 = &lsB[(wv * 32)      * BK];
    unsigned short* lB1 = &lsB[(wv * 32 + 16) * BK];

    const int fr = lane & 15;
    const int kq = (lane >> 4) * 8;

    f32x4 acc[4][4] = {};

    for (int kt = 0; kt < IN_F; kt += BK) {
        async_load16(gA0, lA0);
        async_load16(gA1, lA1);
        async_load16(gB0, lB0);
        async_load16(gB1, lB1);
        gA0 += BK; gA1 += BK; gB0 += BK; gB1 += BK;
        __syncthreads();

        bf16x8 aF[4], bF[4];
        #pragma unroll
        for (int i = 0; i < 4; ++i)
            aF[i] = *(const bf16x8*)&lsA[(wmm + i * 16 + fr) * BK + kq];
        #pragma unroll
        for (int j = 0; j < 4; ++j)
            bF[j] = *(const bf16x8*)&lsB[(wnn + j * 16 + fr) * BK + kq];

        #pragma unroll
        for (int i = 0; i < 4; ++i)
            #pragma unroll
            for (int j = 0; j < 4; ++j)
                acc[i][j] = MFMA(aF[i], bF[j], acc[i][j]);
        __syncthreads();
    }

    const int ocol = n0 + wnn;
    float bj[4];
    #pragma unroll
    for (int j = 0; j < 4; ++j) bj[j] = bias[ocol + j * 16 + fr];

    const int rsel = (lane >> 4) * 4;
    #pragma unroll
    for (int i = 0; i < 4; ++i) {
        #pragma unroll
        for (int v = 0; v < 4; ++v) {
            const int row = m0 + wmm + i * 16 + rsel + v;
            float* orow = out + (size_t)row * OUT_F + ocol + fr;
            #pragma unroll
            for (int j = 0; j < 4; ++j)
                orow[j * 16] = acc[i][j][v] + bj[j];
        }
    }
}

// ---------- fallback: correct fp32 tiled GEMM (only if ws too small) ----------
__global__ void fb_gemm(const float* __restrict__ A, const float* __restrict__ W,
                        const float* __restrict__ bias, float* __restrict__ out) {
    __shared__ float tA[16][17];
    __shared__ float tW[16][17];
    const int tx = threadIdx.x, ty = threadIdx.y;
    const int row = blockIdx.y * 16 + ty;
    const int col = blockIdx.x * 16 + tx;
    float s = 0.f;
    for (int k = 0; k < IN_F; k += 16) {
        tA[ty][tx] = A[(size_t)row * IN_F + k + tx];
        tW[ty][tx] = W[(size_t)(blockIdx.x * 16 + ty) * IN_F + k + tx];
        __syncthreads();
        #pragma unroll
        for (int kk = 0; kk < 16; ++kk) s += tA[ty][kk] * tW[tx][kk];
        __syncthreads();
    }
    out[(size_t)row * OUT_F + col] = s + bias[col];
}

extern "C" void kernel_launch(void* const* d_in, const int* in_sizes, int n_in,
                              void* d_out, int out_size, void* d_ws, size_t ws_size,
                              hipStream_t stream) {
    const float* x = (const float*)d_in[0];
    const float* W = (const float*)d_in[1];
    const float* b = (const float*)d_in[2];
    float* out = (float*)d_out;

    const size_t elems      = (size_t)BATCH * IN_F;  // 16.7M per matrix
    const size_t bf16_bytes = elems * 2;             // 32 MiB each

    if (ws_size >= 2 * bf16_bytes) {
        unsigned short* xb = (unsigned short*)d_ws;
        unsigned short* wb = (unsigned short*)((char*)d_ws + bf16_bytes);

        const int blocks_per = (int)(elems / 8 / 256);   // 8192 per matrix
        cvt2_f32_bf16<<<blocks_per * 2, 256, 0, stream>>>(
            (const float4*)x, (uint4*)xb, (const float4*)W, (uint4*)wb);

        static int use8 = -1;
        if (use8 < 0) {
            use8 = (hipFuncSetAttribute((const void*)gemm_8ph,
                        hipFuncAttributeMaxDynamicSharedMemorySize,
                        131072) == hipSuccess) ? 1 : 0;
        }
        if (use8) {
            gemm_8ph<<<256, 512, 131072, stream>>>(xb, wb, b, out);
        } else {
            dim3 grid(OUT_F / BN, BATCH / BM);
            gemm_bt_bf16<<<grid, 256, 0, stream>>>(xb, wb, b, out);
        }
    } else {
        dim3 grid(OUT_F / 16, BATCH / 16);
        fb_gemm<<<grid, dim3(16, 16), 0, stream>>>(x, W, b, out);
    }
}

// Round 4
// 273.806 us; speedup vs baseline: 1.0567x; 1.0226x over previous
//
#include <hip/hip_runtime.h>
#include <stdint.h>

#define IN_F   4096
#define OUT_F  4096
#define BATCH  4096

// legacy kernel tile params
#define BM 128
#define BN 128
#define BK 32

typedef __bf16 bf16x8 __attribute__((ext_vector_type(8)));
typedef float  f32x4  __attribute__((ext_vector_type(4)));

#define MFMA(a, b, c) __builtin_amdgcn_mfma_f32_16x16x32_bf16(a, b, c, 0, 0, 0)

// ---------- fp32 -> bf16 (round-to-nearest-even) ----------
__device__ inline unsigned short f32_to_bf16_rne(float f) {
    unsigned int u = __float_as_uint(f);
    u += 0x7FFFu + ((u >> 16) & 1u);
    return (unsigned short)(u >> 16);
}

__device__ inline unsigned int pack_bf16x2(float lo, float hi) {
    return (unsigned int)f32_to_bf16_rne(lo) | ((unsigned int)f32_to_bf16_rne(hi) << 16);
}

// One launch converts BOTH x and W. 8 floats/thread: 32B read, 16B write per lane.
__global__ void cvt2_f32_bf16(const float4* __restrict__ ia, uint4* __restrict__ oa,
                              const float4* __restrict__ ib, uint4* __restrict__ ob) {
    const int half = gridDim.x >> 1;
    const int sec  = blockIdx.x >= half;
    const float4* __restrict__ in  = sec ? ib : ia;
    uint4* __restrict__ out        = sec ? ob : oa;
    const int i = (sec ? blockIdx.x - half : blockIdx.x) * blockDim.x + threadIdx.x;
    const float4 u = in[2 * i];
    const float4 v = in[2 * i + 1];
    uint4 o;
    o.x = pack_bf16x2(u.x, u.y);
    o.y = pack_bf16x2(u.z, u.w);
    o.z = pack_bf16x2(v.x, v.y);
    o.w = pack_bf16x2(v.z, v.w);
    out[i] = o;
}

// ---------- async global->LDS, 16B per lane ----------
__device__ inline void async_load16(const void* g, void* l) {
    __builtin_amdgcn_global_load_lds(
        (const __attribute__((address_space(1))) unsigned int*)g,
        (__attribute__((address_space(3))) unsigned int*)l,
        16, 0, 0);
}

// =====================================================================
// 256x256 pipelined bf16 GEMM: C = A * Bt^T + bias
// A: [BATCH][IN_F] bf16 bits, Bt: [OUT_F][IN_F] bf16 bits (K-contiguous)
//
// Geometry: BM=BN=256, BK=64, 512 threads = 8 waves (2M x 4N),
// per-wave output 128x64. LDS 128 KiB: [buf:2][hid:4][16 KiB];
// hid 0=A-ks0 1=A-ks1 2=B-ks0 3=B-ks1. Half-tile = [256 rows][32 elems].
//
// Swizzle (round-3, conflict-free, verified BANK_CONFLICT=0):
//   l = p ^ (((p>>7)&7)<<4). Linear global_load_lds dest + pre-swizzled
//   global SOURCE + swizzled ds_read (both-sides, rule #21).
//
// Round-4 change: READ-AHEAD pipeline. Phase p's MFMA consumes fragments
// whose ds_reads were ISSUED in phase p-1; phase p issues reads for p+1
// AFTER its MFMA cluster -> LDS service overlaps the matrix pipe
// (previously serialized: 1536 read + 512 write + 2064 MFMA clk/tile).
// Per phase: {lgkmcnt(0) [drains last phase's reads]; 16 MFMA;
//             issue next-phase reads; stage; barrier}.
// Operand double-buffer: aX/aY alternate (A quads), bA/bB alternate
// (B quads, each lives 2 phases). 4 barriers/tile:
//   p1: MFMA i0-3@ks0 (aX,bA); read aY<-A47ks0; stage A-ks1(t+1)->buf^1; bar
//   p2: MFMA i4-7@ks0 (aY,bA); read aX<-A03ks1, bB<-B03ks1; stage B-ks0(t+2); bar
//   p3: MFMA i0-3@ks1 (aX,bB); read aY<-A47ks1; stage A-ks0(t+2); bar
//   p4: lgkm; vmcnt(4); bar; read aX,bA <- NEXT buf A03ks0/B03ks0;
//       MFMA i4-7@ks1 (aY,bB); stage B-ks1(t+2)   [no end barrier needed]
//
// vmcnt(4)@p4 proof: outstanding (oldest first) = {Bks0(t+1),Aks0(t+1),
//   Bks1(t+1),Aks1(t+1), Bks0(t+2),Aks0(t+2)} = 12 -> wait to 4 completes
//   ALL of tile t+1; mid-p4 barrier makes it cross-wave before the
//   next-buffer reads issue.
// Slot safety (stage issue >= 1 barrier after slot's readers drained):
//   A-ks1(t+1)@p1: readers drained p4(t-1), barA between  OK
//   B-ks0(t+2)@p2: bA drained p1, p1-end bar between      OK
//   A-ks0(t+2)@p3: aX drained p1, 2 bars between          OK
//   B-ks1(t+2)@p4: bB drained p3, p3-end bar between      OK
// Cross p4->p1 (no barrier): p4 ops touch buf(t) hid3 + buf(t+1) reads;
//   p1(t+1) ops touch buf(t) hid1 + regs -> disjoint slots. Racing-ahead
//   waves' p2(t+1) stage is gated by p1-end barrier, after all waves
//   drained their t+1-p1 reads. Verified disjoint.
// Tail clamp re-stages tile-63 bytes over identical locations (benign).
// Accumulation order per acc element identical to round 3 -> same bits.
// =====================================================================
__global__ __launch_bounds__(512, 2)
void gemm_8ph(const unsigned short* __restrict__ A,
              const unsigned short* __restrict__ Bt,
              const float* __restrict__ bias,
              float* __restrict__ out) {
    extern __shared__ char smem[];

    const int tid  = threadIdx.x;
    const int lane = tid & 63;
    const int wv   = tid >> 6;       // 0..7
    const int wm   = wv >> 2;        // 0..1  (M half: 128 rows)
    const int wn   = wv & 3;         // 0..3  (N quarter: 64 cols)

    // XCD-aware bijective swizzle (256 wgs, 256 % 8 == 0)
    const int bid = blockIdx.x;
    const int swz = (bid & 7) * 32 + (bid >> 3);
    const int m0  = (swz >> 4) * 256;
    const int n0  = (swz & 15) * 256;

    // ---- staging geometry: linear LDS dest, pre-swizzled global src ----
    const int p0   = tid * 16;
    const int l0   = p0 ^ (((p0 >> 7) & 7) << 4);
    const int srow = l0 >> 6;          // 0..127  (q=1 adds 128)
    const int scol = (l0 & 63) >> 1;   // elem 0..31 (multiple of 8)
    const unsigned short* sA = A  + (size_t)(m0 + srow) * IN_F + scol;
    const unsigned short* sB = Bt + (size_t)(n0 + srow) * IN_F + scol;
    char* const ldsw = smem + wv * 1024;   // wave-uniform staging base

    auto stage = [&](const unsigned short* g, int hid, int buf) {
        char* d = ldsw + buf * 65536 + hid * 16384;
        async_load16(g, d);                                  // rows 0..127
        async_load16(g + (size_t)128 * IN_F, d + 8192);      // rows 128..255
    };

    // ---- prologue: tile 0 (4 halves) ----
    stage(sA,      0, 0);   // A-ks0(0)
    stage(sB,      2, 0);   // B-ks0(0)
    stage(sA + 32, 1, 0);   // A-ks1(0)
    stage(sB + 32, 3, 0);   // B-ks1(0)

    // frag-read base offsets. MFMA operand: row = lane&15, k = (lane>>4)*8+j
    // phys = (row*64 + kq2) ^ sx, sx = row bits 1-3 -> bits 4-6 (lane-only).
    // frag i adds i*1024 (bits >=10, commutes with XOR) -> immediate offsets.
    const int fr  = lane & 15;
    const int kq2 = ((lane >> 4) << 3) * 2;      // 0,16,32,48
    const int sx  = (fr & 14) << 3;              // swizzle mask, bits 4-6
    const int aroBase = ((wm * 128 + fr) * 64 + kq2) ^ sx;
    const int broBase = ((wn * 64  + fr) * 64 + kq2) ^ sx;
    const char* vA0 = smem + aroBase;            // A @ buf0: ks0 +0, ks1 +16384, frag +i*1024
    const char* vB0 = smem + 32768 + broBase;    // B @ buf0: ks0 +0, ks1 +16384, frag +j*1024
    const char* vA1 = vA0 + 65536;               // buf1 variants
    const char* vB1 = vB0 + 65536;

    f32x4 acc[8][4] = {};
    bf16x8 aX[4], aY[4], bAq[4], bBq[4];

    // prime tile-1 halves to match steady-state issue order (p2,p3 of t-1)
    stage(sB + 64, 2, 1);   // B-ks0(1)
    stage(sA + 64, 0, 1);   // A-ks0(1)
    asm volatile("s_waitcnt vmcnt(4)" ::: "memory");   // tile 0 fully staged
    __builtin_amdgcn_s_barrier();
    #pragma unroll
    for (int i = 0; i < 4; ++i) aX[i]  = *(const bf16x8*)(vA0 + i * 1024);
    #pragma unroll
    for (int j = 0; j < 4; ++j) bAq[j] = *(const bf16x8*)(vB0 + j * 1024);
    stage(sB + 96, 3, 1);   // B-ks1(1)  -> 6 loads in flight = steady state

#define TILE_BODY(cA, cB, nA, nB, CB, KT1, KT2)                               \
  {                                                                           \
    /* ---- p1: MFMA i0-3@ks0 ---- */                                         \
    asm volatile("s_waitcnt lgkmcnt(0)" ::: "memory");                        \
    __builtin_amdgcn_s_setprio(1);                                            \
    _Pragma("unroll") for (int i = 0; i < 4; ++i)                             \
      _Pragma("unroll") for (int j = 0; j < 4; ++j)                           \
        acc[i][j] = MFMA(aX[i], bAq[j], acc[i][j]);                           \
    __builtin_amdgcn_s_setprio(0);                                            \
    _Pragma("unroll") for (int i = 0; i < 4; ++i)                             \
      aY[i] = *(const bf16x8*)((cA) + 4096 + i * 1024);                       \
    stage(sA + (KT1) + 32, 1, (CB) ^ 1);                                      \
    __builtin_amdgcn_s_barrier();                                             \
    /* ---- p2: MFMA i4-7@ks0 ---- */                                         \
    asm volatile("s_waitcnt lgkmcnt(0)" ::: "memory");                        \
    __builtin_amdgcn_s_setprio(1);                                            \
    _Pragma("unroll") for (int i = 0; i < 4; ++i)                             \
      _Pragma("unroll") for (int j = 0; j < 4; ++j)                           \
        acc[4 + i][j] = MFMA(aY[i], bAq[j], acc[4 + i][j]);                   \
    __builtin_amdgcn_s_setprio(0);                                            \
    _Pragma("unroll") for (int i = 0; i < 4; ++i)                             \
      aX[i] = *(const bf16x8*)((cA) + 16384 + i * 1024);                      \
    _Pragma("unroll") for (int j = 0; j < 4; ++j)                             \
      bBq[j] = *(const bf16x8*)((cB) + 16384 + j * 1024);                     \
    stage(sB + (KT2), 2, (CB));                                               \
    __builtin_amdgcn_s_barrier();                                             \
    /* ---- p3: MFMA i0-3@ks1 ---- */                                         \
    asm volatile("s_waitcnt lgkmcnt(0)" ::: "memory");                        \
    __builtin_amdgcn_s_setprio(1);                                            \
    _Pragma("unroll") for (int i = 0; i < 4; ++i)                             \
      _Pragma("unroll") for (int j = 0; j < 4; ++j)                           \
        acc[i][j] = MFMA(aX[i], bBq[j], acc[i][j]);                           \
    __builtin_amdgcn_s_setprio(0);                                            \
    _Pragma("unroll") for (int i = 0; i < 4; ++i)                             \
      aY[i] = *(const bf16x8*)((cA) + 16384 + 4096 + i * 1024);               \
    stage(sA + (KT2), 0, (CB));                                               \
    __builtin_amdgcn_s_barrier();                                             \
    /* ---- p4: MFMA i4-7@ks1 + tile handoff ---- */                          \
    asm volatile("s_waitcnt lgkmcnt(0)" ::: "memory");                        \
    asm volatile("s_waitcnt vmcnt(4)" ::: "memory");                          \
    __builtin_amdgcn_s_barrier();                                             \
    _Pragma("unroll") for (int i = 0; i < 4; ++i)                             \
      aX[i] = *(const bf16x8*)((nA) + i * 1024);                              \
    _Pragma("unroll") for (int j = 0; j < 4; ++j)                             \
      bAq[j] = *(const bf16x8*)((nB) + j * 1024);                             \
    __builtin_amdgcn_s_setprio(1);                                            \
    _Pragma("unroll") for (int i = 0; i < 4; ++i)                             \
      _Pragma("unroll") for (int j = 0; j < 4; ++j)                           \
        acc[4 + i][j] = MFMA(aY[i], bBq[j], acc[4 + i][j]);                   \
    __builtin_amdgcn_s_setprio(0);                                            \
    stage(sB + (KT2) + 32, 3, (CB));                                          \
  }

    for (int tt = 0; tt < 64; tt += 2) {
        // even tile: buf0 current, buf1 next
        {
            const int kt1 = (tt + 1) * 64;                        // tt+1 <= 63
            const int kt2 = (tt + 2 < 64 ? tt + 2 : 63) * 64;
            TILE_BODY(vA0, vB0, vA1, vB1, 0, kt1, kt2);
        }
        // odd tile: buf1 current, buf0 next
        {
            const int t   = tt + 1;
            const int kt1 = (t + 1 < 64 ? t + 1 : 63) * 64;
            const int kt2 = (t + 2 < 64 ? t + 2 : 63) * 64;
            TILE_BODY(vA1, vB1, vA0, vB0, 1, kt1, kt2);
        }
    }
#undef TILE_BODY

    asm volatile("s_waitcnt vmcnt(0) lgkmcnt(0)" ::: "memory");  // drain tail

    // ---- epilogue. C/D layout (verified m89/m91): col=lane&15, row=(lane>>4)*4+reg ----
    const int ocol = n0 + wn * 64;
    int oc = ocol + fr;
    asm volatile("" : "+v"(oc));   // launder: keep bias loads out of the counted loop
    float bj[4];
    #pragma unroll
    for (int j = 0; j < 4; ++j) bj[j] = bias[oc + j * 16];
    const int rsel = (lane >> 4) * 4;
    #pragma unroll
    for (int i = 0; i < 8; ++i) {
        #pragma unroll
        for (int v = 0; v < 4; ++v) {
            const int row = m0 + wm * 128 + i * 16 + rsel + v;
            float* orow = out + (size_t)row * OUT_F + ocol + fr;
            #pragma unroll
            for (int j = 0; j < 4; ++j)
                orow[j * 16] = acc[i][j][v] + bj[j];
        }
    }
}

// =====================================================================
// Legacy verified m97-structure kernel — fallback if 128 KiB dyn-LDS
// attribute can't be set.
// =====================================================================
__global__ void gemm_bt_bf16(const unsigned short* __restrict__ A,
                             const unsigned short* __restrict__ Bt,
                             const float* __restrict__ bias,
                             float* __restrict__ out) {
    __shared__ unsigned short lsA[BM * BK];
    __shared__ unsigned short lsB[BN * BK];

    const int tid  = threadIdx.x;
    const int lane = tid & 63;
    const int wv   = tid >> 6;
    const int wmm  = (wv & 1) * 64;
    const int wnn  = (wv >> 1) * 64;

    const int m0 = blockIdx.y * BM;
    const int n0 = blockIdx.x * BN;

    const int srow = lane >> 2;
    const int scol = (lane & 3) * 8;

    const unsigned short* gA0 = A  + (size_t)(m0 + wv * 32 + srow) * IN_F + scol;
    const unsigned short* gA1 = gA0 + 16 * (size_t)IN_F;
    const unsigned short* gB0 = Bt + (size_t)(n0 + wv * 32 + srow) * IN_F + scol;
    const unsigned short* gB1 = gB0 + 16 * (size_t)IN_F;

    unsigned short* lA0 = &lsA[(wv * 32)      * BK];
    unsigned short* lA1 = &lsA[(wv * 32 + 16) * BK];
    unsigned short* lB0 = &lsB[(wv * 32)      * BK];
    unsigned short* lB1 = &lsB[(wv * 32 + 16) * BK];

    const int fr = lane & 15;
    const int kq = (lane >> 4) * 8;

    f32x4 acc[4][4] = {};

    for (int kt = 0; kt < IN_F; kt += BK) {
        async_load16(gA0, lA0);
        async_load16(gA1, lA1);
        async_load16(gB0, lB0);
        async_load16(gB1, lB1);
        gA0 += BK; gA1 += BK; gB0 += BK; gB1 += BK;
        __syncthreads();

        bf16x8 aF[4], bF[4];
        #pragma unroll
        for (int i = 0; i < 4; ++i)
            aF[i] = *(const bf16x8*)&lsA[(wmm + i * 16 + fr) * BK + kq];
        #pragma unroll
        for (int j = 0; j < 4; ++j)
            bF[j] = *(const bf16x8*)&lsB[(wnn + j * 16 + fr) * BK + kq];

        #pragma unroll
        for (int i = 0; i < 4; ++i)
            #pragma unroll
            for (int j = 0; j < 4; ++j)
                acc[i][j] = MFMA(aF[i], bF[j], acc[i][j]);
        __syncthreads();
    }

    const int ocol = n0 + wnn;
    float bj[4];
    #pragma unroll
    for (int j = 0; j < 4; ++j) bj[j] = bias[ocol + j * 16 + fr];

    const int rsel = (lane >> 4) * 4;
    #pragma unroll
    for (int i = 0; i < 4; ++i) {
        #pragma unroll
        for (int v = 0; v < 4; ++v) {
            const int row = m0 + wmm + i * 16 + rsel + v;
            float* orow = out + (size_t)row * OUT_F + ocol + fr;
            #pragma unroll
            for (int j = 0; j < 4; ++j)
                orow[j * 16] = acc[i][j][v] + bj[j];
        }
    }
}

// ---------- fallback: correct fp32 tiled GEMM (only if ws too small) ----------
__global__ void fb_gemm(const float* __restrict__ A, const float* __restrict__ W,
                        const float* __restrict__ bias, float* __restrict__ out) {
    __shared__ float tA[16][17];
    __shared__ float tW[16][17];
    const int tx = threadIdx.x, ty = threadIdx.y;
    const int row = blockIdx.y * 16 + ty;
    const int col = blockIdx.x * 16 + tx;
    float s = 0.f;
    for (int k = 0; k < IN_F; k += 16) {
        tA[ty][tx] = A[(size_t)row * IN_F + k + tx];
        tW[ty][tx] = W[(size_t)(blockIdx.x * 16 + ty) * IN_F + k + tx];
        __syncthreads();
        #pragma unroll
        for (int kk = 0; kk < 16; ++kk) s += tA[ty][kk] * tW[tx][kk];
        __syncthreads();
    }
    out[(size_t)row * OUT_F + col] = s + bias[col];
}

extern "C" void kernel_launch(void* const* d_in, const int* in_sizes, int n_in,
                              void* d_out, int out_size, void* d_ws, size_t ws_size,
                              hipStream_t stream) {
    const float* x = (const float*)d_in[0];
    const float* W = (const float*)d_in[1];
    const float* b = (const float*)d_in[2];
    float* out = (float*)d_out;

    const size_t elems      = (size_t)BATCH * IN_F;  // 16.7M per matrix
    const size_t bf16_bytes = elems * 2;             // 32 MiB each

    if (ws_size >= 2 * bf16_bytes) {
        unsigned short* xb = (unsigned short*)d_ws;
        unsigned short* wb = (unsigned short*)((char*)d_ws + bf16_bytes);

        const int blocks_per = (int)(elems / 8 / 256);   // 8192 per matrix
        cvt2_f32_bf16<<<blocks_per * 2, 256, 0, stream>>>(
            (const float4*)x, (uint4*)xb, (const float4*)W, (uint4*)wb);

        static int use8 = -1;
        if (use8 < 0) {
            use8 = (hipFuncSetAttribute((const void*)gemm_8ph,
                        hipFuncAttributeMaxDynamicSharedMemorySize,
                        131072) == hipSuccess) ? 1 : 0;
        }
        if (use8) {
            gemm_8ph<<<256, 512, 131072, stream>>>(xb, wb, b, out);
        } else {
            dim3 grid(OUT_F / BN, BATCH / BM);
            gemm_bt_bf16<<<grid, 256, 0, stream>>>(xb, wb, b, out);
        }
    } else {
        dim3 grid(OUT_F / 16, BATCH / 16);
        fb_gemm<<<grid, dim3(16, 16), 0, stream>>>(x, W, b, out);
    }
}

// Round 5
// 273.652 us; speedup vs baseline: 1.0573x; 1.0006x over previous
//
#include <hip/hip_runtime.h>
#include <stdint.h>

#define IN_F   4096
#define OUT_F  4096
#define BATCH  4096

// legacy kernel tile params
#define BM 128
#define BN 128
#define BK 32

typedef __bf16 bf16x8 __attribute__((ext_vector_type(8)));
typedef float  f32x4  __attribute__((ext_vector_type(4)));

#define MFMA(a, b, c) __builtin_amdgcn_mfma_f32_16x16x32_bf16(a, b, c, 0, 0, 0)

// ---------- fp32 -> bf16 (round-to-nearest-even) ----------
__device__ inline unsigned short f32_to_bf16_rne(float f) {
    unsigned int u = __float_as_uint(f);
    u += 0x7FFFu + ((u >> 16) & 1u);
    return (unsigned short)(u >> 16);
}

__device__ inline unsigned int pack_bf16x2(float lo, float hi) {
    return (unsigned int)f32_to_bf16_rne(lo) | ((unsigned int)f32_to_bf16_rne(hi) << 16);
}

// One launch converts BOTH x and W. 8 floats/thread: 32B read, 16B write per lane.
__global__ void cvt2_f32_bf16(const float4* __restrict__ ia, uint4* __restrict__ oa,
                              const float4* __restrict__ ib, uint4* __restrict__ ob) {
    const int half = gridDim.x >> 1;
    const int sec  = blockIdx.x >= half;
    const float4* __restrict__ in  = sec ? ib : ia;
    uint4* __restrict__ out        = sec ? ob : oa;
    const int i = (sec ? blockIdx.x - half : blockIdx.x) * blockDim.x + threadIdx.x;
    const float4 u = in[2 * i];
    const float4 v = in[2 * i + 1];
    uint4 o;
    o.x = pack_bf16x2(u.x, u.y);
    o.y = pack_bf16x2(u.z, u.w);
    o.z = pack_bf16x2(v.x, v.y);
    o.w = pack_bf16x2(v.z, v.w);
    out[i] = o;
}

// ---------- async global->LDS, 16B per lane ----------
__device__ inline void async_load16(const void* g, void* l) {
    __builtin_amdgcn_global_load_lds(
        (const __attribute__((address_space(1))) unsigned int*)g,
        (__attribute__((address_space(3))) unsigned int*)l,
        16, 0, 0);
}

// =====================================================================
// 256x256 pipelined bf16 GEMM: C = A * Bt^T + bias
// A: [BATCH][IN_F] bf16 bits, Bt: [OUT_F][IN_F] bf16 bits (K-contiguous)
//
// Geometry: BM=BN=256, BK=64, 512 threads = 8 waves (2M x 4N),
// per-wave output 128x64. LDS 128 KiB: [buf:2][hid:4][16 KiB];
// hid 0=A-ks0 1=A-ks1 2=B-ks0 3=B-ks1. Half-tile = [256 rows][32 elems].
//
// Swizzle (round-3, conflict-free, verified BANK_CONFLICT=0):
//   l = p ^ (((p>>7)&7)<<4). Linear global_load_lds dest + pre-swizzled
//   global SOURCE + swizzled ds_read (both-sides, rule #21).
//
// Round-5 change: ds_reads for phase p+1 issue at the TOP of phase p
// (right after the lgkmcnt(0) drain), BEFORE the MFMA cluster. Round 4
// issued them after the MFMAs, so their LDS service (up to 64 reads x
// 1KB across 8 lockstepped waves = ~256 clk) was exposed at the barrier
// instead of hidden under the ~620-clk MFMA cluster. Reads target the
// alternate operand register set (aY vs aX, bAq vs bBq) -> no dependency
// with the current MFMAs. Stage issue also moves pre-MFMA (same phase ->
// identical vmcnt positions; earlier HBM fetch start).
// Per phase: {lgkm0; [p4: vmcnt(4); bar]; reads(p+1); stage; setprio;
//             16 MFMA; setprio; bar}.
//   p1: reads aY<-A47ks0(buf);            stage A-ks1(t+1)->buf^1; MFMA i0-3@ks0 (aX,bAq)
//   p2: reads aX<-A03ks1, bB<-B03ks1;     stage B-ks0(t+2)->buf;   MFMA i4-7@ks0 (aY,bAq)
//   p3: reads aY<-A47ks1;                 stage A-ks0(t+2)->buf;   MFMA i0-3@ks1 (aX,bBq)
//   p4: lgkm; vmcnt(4); bar; reads aX,bA<-NEXT buf A03ks0/B03ks0;
//       stage B-ks1(t+2)->buf;            MFMA i4-7@ks1 (aY,bBq)   [no end bar]
//
// vmcnt(4)@p4 proof (stage order p1:Aks1(t+1), p2:Bks0(t+2), p3:Aks0(t+2),
//   p4:Bks1(t+2) — unchanged from round 4): outstanding at p4 =
//   {Bks0(t+1),Aks0(t+1),Bks1(t+1),Aks1(t+1),Bks0(t+2),Aks0(t+2)} = 12
//   loads -> wait to 4 completes ALL of tile t+1; mid-p4 barrier makes it
//   cross-wave before the next-buffer reads issue.
// Slot safety (stage issue >= 1 barrier after ALL waves drained slot):
//   p1 stage hid1(buf^1): readers drained p3(t-1)/p4(t-1) lgkm0, all
//     before p4's mid-barrier -> OK
//   p2 stage hid2(buf): bAq (read p4(t-1)) drained p1 lgkm0; p1-end bar OK
//   p3 stage hid0(buf): aY@p1 drained p2 lgkm0; p2-end bar OK
//   p4 stage hid3(buf): bBq@p2 drained p3 lgkm0; p3-end bar + mid-bar OK
//   Same-phase read/stage hids disjoint (p1:0/1, p2:1,3/2, p3:1/0,
//   p4:nextbuf 0,2 / curbuf 3).
// Tail clamp re-stages tile-63 bytes over identical locations (benign).
// Accumulation order per acc element identical to round 3/4 -> same bits.
// =====================================================================
__global__ __launch_bounds__(512, 2)
void gemm_8ph(const unsigned short* __restrict__ A,
              const unsigned short* __restrict__ Bt,
              const float* __restrict__ bias,
              float* __restrict__ out) {
    extern __shared__ char smem[];

    const int tid  = threadIdx.x;
    const int lane = tid & 63;
    const int wv   = tid >> 6;       // 0..7
    const int wm   = wv >> 2;        // 0..1  (M half: 128 rows)
    const int wn   = wv & 3;         // 0..3  (N quarter: 64 cols)

    // XCD-aware bijective swizzle (256 wgs, 256 % 8 == 0)
    const int bid = blockIdx.x;
    const int swz = (bid & 7) * 32 + (bid >> 3);
    const int m0  = (swz >> 4) * 256;
    const int n0  = (swz & 15) * 256;

    // ---- staging geometry: linear LDS dest, pre-swizzled global src ----
    const int p0   = tid * 16;
    const int l0   = p0 ^ (((p0 >> 7) & 7) << 4);
    const int srow = l0 >> 6;          // 0..127  (q=1 adds 128)
    const int scol = (l0 & 63) >> 1;   // elem 0..31 (multiple of 8)
    const unsigned short* sA = A  + (size_t)(m0 + srow) * IN_F + scol;
    const unsigned short* sB = Bt + (size_t)(n0 + srow) * IN_F + scol;
    char* const ldsw = smem + wv * 1024;   // wave-uniform staging base

    auto stage = [&](const unsigned short* g, int hid, int buf) {
        char* d = ldsw + buf * 65536 + hid * 16384;
        async_load16(g, d);                                  // rows 0..127
        async_load16(g + (size_t)128 * IN_F, d + 8192);      // rows 128..255
    };

    // ---- prologue: tile 0 (4 halves) ----
    stage(sA,      0, 0);   // A-ks0(0)
    stage(sB,      2, 0);   // B-ks0(0)
    stage(sA + 32, 1, 0);   // A-ks1(0)
    stage(sB + 32, 3, 0);   // B-ks1(0)

    // frag-read base offsets. MFMA operand: row = lane&15, k = (lane>>4)*8+j
    // phys = (row*64 + kq2) ^ sx, sx = row bits 1-3 -> bits 4-6 (lane-only).
    // frag i adds i*1024 (bits >=10, commutes with XOR) -> immediate offsets.
    const int fr  = lane & 15;
    const int kq2 = ((lane >> 4) << 3) * 2;      // 0,16,32,48
    const int sx  = (fr & 14) << 3;              // swizzle mask, bits 4-6
    const int aroBase = ((wm * 128 + fr) * 64 + kq2) ^ sx;
    const int broBase = ((wn * 64  + fr) * 64 + kq2) ^ sx;
    const char* vA0 = smem + aroBase;            // A @ buf0: ks0 +0, ks1 +16384, frag +i*1024
    const char* vB0 = smem + 32768 + broBase;    // B @ buf0: ks0 +0, ks1 +16384, frag +j*1024
    const char* vA1 = vA0 + 65536;               // buf1 variants
    const char* vB1 = vB0 + 65536;

    f32x4 acc[8][4] = {};
    bf16x8 aX[4], aY[4], bAq[4], bBq[4];

    // prime tile-1 halves to match steady-state issue order (p2,p3 of t-1)
    stage(sB + 64, 2, 1);   // B-ks0(1)
    stage(sA + 64, 0, 1);   // A-ks0(1)
    asm volatile("s_waitcnt vmcnt(4)" ::: "memory");   // tile 0 fully staged
    __builtin_amdgcn_s_barrier();
    #pragma unroll
    for (int i = 0; i < 4; ++i) aX[i]  = *(const bf16x8*)(vA0 + i * 1024);
    #pragma unroll
    for (int j = 0; j < 4; ++j) bAq[j] = *(const bf16x8*)(vB0 + j * 1024);
    stage(sB + 96, 3, 1);   // B-ks1(1)  -> 6 loads in flight = steady state

#define TILE_BODY(cA, cB, nA, nB, CB, KT1, KT2)                               \
  {                                                                           \
    /* ---- p1: reads aY; stage; MFMA i0-3@ks0 (aX,bAq) ---- */               \
    asm volatile("s_waitcnt lgkmcnt(0)" ::: "memory");                        \
    _Pragma("unroll") for (int i = 0; i < 4; ++i)                             \
      aY[i] = *(const bf16x8*)((cA) + 4096 + i * 1024);                       \
    stage(sA + (KT1) + 32, 1, (CB) ^ 1);                                      \
    __builtin_amdgcn_s_setprio(1);                                            \
    _Pragma("unroll") for (int i = 0; i < 4; ++i)                             \
      _Pragma("unroll") for (int j = 0; j < 4; ++j)                           \
        acc[i][j] = MFMA(aX[i], bAq[j], acc[i][j]);                           \
    __builtin_amdgcn_s_setprio(0);                                            \
    __builtin_amdgcn_s_barrier();                                             \
    /* ---- p2: reads aX,bBq; stage; MFMA i4-7@ks0 (aY,bAq) ---- */           \
    asm volatile("s_waitcnt lgkmcnt(0)" ::: "memory");                        \
    _Pragma("unroll") for (int i = 0; i < 4; ++i)                             \
      aX[i] = *(const bf16x8*)((cA) + 16384 + i * 1024);                      \
    _Pragma("unroll") for (int j = 0; j < 4; ++j)                             \
      bBq[j] = *(const bf16x8*)((cB) + 16384 + j * 1024);                     \
    stage(sB + (KT2), 2, (CB));                                               \
    __builtin_amdgcn_s_setprio(1);                                            \
    _Pragma("unroll") for (int i = 0; i < 4; ++i)                             \
      _Pragma("unroll") for (int j = 0; j < 4; ++j)                           \
        acc[4 + i][j] = MFMA(aY[i], bAq[j], acc[4 + i][j]);                   \
    __builtin_amdgcn_s_setprio(0);                                            \
    __builtin_amdgcn_s_barrier();                                             \
    /* ---- p3: reads aY; stage; MFMA i0-3@ks1 (aX,bBq) ---- */               \
    asm volatile("s_waitcnt lgkmcnt(0)" ::: "memory");                        \
    _Pragma("unroll") for (int i = 0; i < 4; ++i)                             \
      aY[i] = *(const bf16x8*)((cA) + 16384 + 4096 + i * 1024);               \
    stage(sA + (KT2), 0, (CB));                                               \
    __builtin_amdgcn_s_setprio(1);                                            \
    _Pragma("unroll") for (int i = 0; i < 4; ++i)                             \
      _Pragma("unroll") for (int j = 0; j < 4; ++j)                           \
        acc[i][j] = MFMA(aX[i], bBq[j], acc[i][j]);                           \
    __builtin_amdgcn_s_setprio(0);                                            \
    __builtin_amdgcn_s_barrier();                                             \
    /* ---- p4: handoff; reads aX,bAq<-next buf; stage; MFMA i4-7@ks1 ---- */ \
    asm volatile("s_waitcnt lgkmcnt(0)" ::: "memory");                        \
    asm volatile("s_waitcnt vmcnt(4)" ::: "memory");                          \
    __builtin_amdgcn_s_barrier();                                             \
    _Pragma("unroll") for (int i = 0; i < 4; ++i)                             \
      aX[i] = *(const bf16x8*)((nA) + i * 1024);                              \
    _Pragma("unroll") for (int j = 0; j < 4; ++j)                             \
      bAq[j] = *(const bf16x8*)((nB) + j * 1024);                             \
    stage(sB + (KT2) + 32, 3, (CB));                                          \
    __builtin_amdgcn_s_setprio(1);                                            \
    _Pragma("unroll") for (int i = 0; i < 4; ++i)                             \
      _Pragma("unroll") for (int j = 0; j < 4; ++j)                           \
        acc[4 + i][j] = MFMA(aY[i], bBq[j], acc[4 + i][j]);                   \
    __builtin_amdgcn_s_setprio(0);                                            \
  }

    for (int tt = 0; tt < 64; tt += 2) {
        // even tile: buf0 current, buf1 next
        {
            const int kt1 = (tt + 1) * 64;                        // tt+1 <= 63
            const int kt2 = (tt + 2 < 64 ? tt + 2 : 63) * 64;
            TILE_BODY(vA0, vB0, vA1, vB1, 0, kt1, kt2);
        }
        // odd tile: buf1 current, buf0 next
        {
            const int t   = tt + 1;
            const int kt1 = (t + 1 < 64 ? t + 1 : 63) * 64;
            const int kt2 = (t + 2 < 64 ? t + 2 : 63) * 64;
            TILE_BODY(vA1, vB1, vA0, vB0, 1, kt1, kt2);
        }
    }
#undef TILE_BODY

    asm volatile("s_waitcnt vmcnt(0) lgkmcnt(0)" ::: "memory");  // drain tail

    // ---- epilogue. C/D layout (verified m89/m91): col=lane&15, row=(lane>>4)*4+reg ----
    const int ocol = n0 + wn * 64;
    int oc = ocol + fr;
    asm volatile("" : "+v"(oc));   // launder: keep bias loads out of the counted loop
    float bj[4];
    #pragma unroll
    for (int j = 0; j < 4; ++j) bj[j] = bias[oc + j * 16];
    const int rsel = (lane >> 4) * 4;
    #pragma unroll
    for (int i = 0; i < 8; ++i) {
        #pragma unroll
        for (int v = 0; v < 4; ++v) {
            const int row = m0 + wm * 128 + i * 16 + rsel + v;
            float* orow = out + (size_t)row * OUT_F + ocol + fr;
            #pragma unroll
            for (int j = 0; j < 4; ++j)
                orow[j * 16] = acc[i][j][v] + bj[j];
        }
    }
}

// =====================================================================
// Legacy verified m97-structure kernel — fallback if 128 KiB dyn-LDS
// attribute can't be set.
// =====================================================================
__global__ void gemm_bt_bf16(const unsigned short* __restrict__ A,
                             const unsigned short* __restrict__ Bt,
                             const float* __restrict__ bias,
                             float* __restrict__ out) {
    __shared__ unsigned short lsA[BM * BK];
    __shared__ unsigned short lsB[BN * BK];

    const int tid  = threadIdx.x;
    const int lane = tid & 63;
    const int wv   = tid >> 6;
    const int wmm  = (wv & 1) * 64;
    const int wnn  = (wv >> 1) * 64;

    const int m0 = blockIdx.y * BM;
    const int n0 = blockIdx.x * BN;

    const int srow = lane >> 2;
    const int scol = (lane & 3) * 8;

    const unsigned short* gA0 = A  + (size_t)(m0 + wv * 32 + srow) * IN_F + scol;
    const unsigned short* gA1 = gA0 + 16 * (size_t)IN_F;
    const unsigned short* gB0 = Bt + (size_t)(n0 + wv * 32 + srow) * IN_F + scol;
    const unsigned short* gB1 = gB0 + 16 * (size_t)IN_F;

    unsigned short* lA0 = &lsA[(wv * 32)      * BK];
    unsigned short* lA1 = &lsA[(wv * 32 + 16) * BK];
    unsigned short* lB0 = &lsB[(wv * 32)      * BK];
    unsigned short* lB1 = &lsB[(wv * 32 + 16) * BK];

    const int fr = lane & 15;
    const int kq = (lane >> 4) * 8;

    f32x4 acc[4][4] = {};

    for (int kt = 0; kt < IN_F; kt += BK) {
        async_load16(gA0, lA0);
        async_load16(gA1, lA1);
        async_load16(gB0, lB0);
        async_load16(gB1, lB1);
        gA0 += BK; gA1 += BK; gB0 += BK; gB1 += BK;
        __syncthreads();

        bf16x8 aF[4], bF[4];
        #pragma unroll
        for (int i = 0; i < 4; ++i)
            aF[i] = *(const bf16x8*)&lsA[(wmm + i * 16 + fr) * BK + kq];
        #pragma unroll
        for (int j = 0; j < 4; ++j)
            bF[j] = *(const bf16x8*)&lsB[(wnn + j * 16 + fr) * BK + kq];

        #pragma unroll
        for (int i = 0; i < 4; ++i)
            #pragma unroll
            for (int j = 0; j < 4; ++j)
                acc[i][j] = MFMA(aF[i], bF[j], acc[i][j]);
        __syncthreads();
    }

    const int ocol = n0 + wnn;
    float bj[4];
    #pragma unroll
    for (int j = 0; j < 4; ++j) bj[j] = bias[ocol + j * 16 + fr];

    const int rsel = (lane >> 4) * 4;
    #pragma unroll
    for (int i = 0; i < 4; ++i) {
        #pragma unroll
        for (int v = 0; v < 4; ++v) {
            const int row = m0 + wmm + i * 16 + rsel + v;
            float* orow = out + (size_t)row * OUT_F + ocol + fr;
            #pragma unroll
            for (int j = 0; j < 4; ++j)
                orow[j * 16] = acc[i][j][v] + bj[j];
        }
    }
}

// ---------- fallback: correct fp32 tiled GEMM (only if ws too small) ----------
__global__ void fb_gemm(const float* __restrict__ A, const float* __restrict__ W,
                        const float* __restrict__ bias, float* __restrict__ out) {
    __shared__ float tA[16][17];
    __shared__ float tW[16][17];
    const int tx = threadIdx.x, ty = threadIdx.y;
    const int row = blockIdx.y * 16 + ty;
    const int col = blockIdx.x * 16 + tx;
    float s = 0.f;
    for (int k = 0; k < IN_F; k += 16) {
        tA[ty][tx] = A[(size_t)row * IN_F + k + tx];
        tW[ty][tx] = W[(size_t)(blockIdx.x * 16 + ty) * IN_F + k + tx];
        __syncthreads();
        #pragma unroll
        for (int kk = 0; kk < 16; ++kk) s += tA[ty][kk] * tW[tx][kk];
        __syncthreads();
    }
    out[(size_t)row * OUT_F + col] = s + bias[col];
}

extern "C" void kernel_launch(void* const* d_in, const int* in_sizes, int n_in,
                              void* d_out, int out_size, void* d_ws, size_t ws_size,
                              hipStream_t stream) {
    const float* x = (const float*)d_in[0];
    const float* W = (const float*)d_in[1];
    const float* b = (const float*)d_in[2];
    float* out = (float*)d_out;

    const size_t elems      = (size_t)BATCH * IN_F;  // 16.7M per matrix
    const size_t bf16_bytes = elems * 2;             // 32 MiB each

    if (ws_size >= 2 * bf16_bytes) {
        unsigned short* xb = (unsigned short*)d_ws;
        unsigned short* wb = (unsigned short*)((char*)d_ws + bf16_bytes);

        const int blocks_per = (int)(elems / 8 / 256);   // 8192 per matrix
        cvt2_f32_bf16<<<blocks_per * 2, 256, 0, stream>>>(
            (const float4*)x, (uint4*)xb, (const float4*)W, (uint4*)wb);

        static int use8 = -1;
        if (use8 < 0) {
            use8 = (hipFuncSetAttribute((const void*)gemm_8ph,
                        hipFuncAttributeMaxDynamicSharedMemorySize,
                        131072) == hipSuccess) ? 1 : 0;
        }
        if (use8) {
            gemm_8ph<<<256, 512, 131072, stream>>>(xb, wb, b, out);
        } else {
            dim3 grid(OUT_F / BN, BATCH / BM);
            gemm_bt_bf16<<<grid, 256, 0, stream>>>(xb, wb, b, out);
        }
    } else {
        dim3 grid(OUT_F / 16, BATCH / 16);
        fb_gemm<<<grid, dim3(16, 16), 0, stream>>>(x, W, b, out);
    }
}